// Round 7
// baseline (413.370 us; speedup 1.0000x reference)
//
#include <hip/hip_runtime.h>
#include <hip/hip_cooperative_groups.h>
#include <stdint.h>

namespace cg = cooperative_groups;

#define DEVFN __device__ __forceinline__

typedef short s16x8 __attribute__((ext_vector_type(8)));
typedef __bf16 bf16x8 __attribute__((ext_vector_type(8)));
typedef float fx4 __attribute__((ext_vector_type(4)));

// Problem constants (fixed by the reference)
constexpr int SEQ = 8192, DIM = 1280, HEADS = 16;
constexpr int NIMG = 32;
constexpr int NQKV = 3840;  // 3*DIM
constexpr int TS = 84;      // raw Q/K tile stride (168B rows: scatter = 2 lanes/bank, free)

DEVFN unsigned short f2bf(float f) {
  union { float f; unsigned u; } v; v.f = f;
  unsigned r = v.u + 0x7FFFu + ((v.u >> 16) & 1u);  // RNE
  return (unsigned short)(r >> 16);
}
DEVFN float bf2f(unsigned short u) {
  union { unsigned u; float f; } v; v.u = ((unsigned)u) << 16;
  return v.f;
}

DEVFN fx4 mfma16(s16x8 a, s16x8 b, fx4 c) {
  return __builtin_amdgcn_mfma_f32_16x16x32_bf16(
      __builtin_bit_cast(bf16x8, a), __builtin_bit_cast(bf16x8, b), c, 0, 0, 0);
}

DEVFN void gload_lds16(const void* g, void* l) {
  // global -> LDS direct, 16B per lane; LDS dest = wave-uniform base + lane*16
  __builtin_amdgcn_global_load_lds(
      (__attribute__((address_space(1))) void*)(uintptr_t)g,
      (__attribute__((address_space(3))) void*)l, 16, 0, 0);
}

// ---------------- fused prep: cast hidden + transpose-cast both weights ----------------
__global__ __launch_bounds__(256) void prep_kernel(const float* __restrict__ hidden,
                                                   unsigned short* __restrict__ hb,
                                                   const float* __restrict__ w_qkv,
                                                   unsigned short* __restrict__ wqkvT,
                                                   const float* __restrict__ w_proj,
                                                   unsigned short* __restrict__ wprojT) {
  const int b = blockIdx.x;
  if (b < 10240) {  // cast: 10240*256*4 = SEQ*DIM exactly
    const int i = b * 256 + threadIdx.x;
    float4 v = ((const float4*)hidden)[i];
    ushort4 o;
    o.x = f2bf(v.x); o.y = f2bf(v.y); o.z = f2bf(v.z); o.w = f2bf(v.w);
    ((ushort4*)hb)[i] = o;
    return;
  }
  __shared__ float tile[32][33];
  const float* W; unsigned short* T;
  int K, N, bx, by;
  if (b < 15040) {
    const int bb = b - 10240;
    bx = bb % 120; by = bb / 120; W = w_qkv; T = wqkvT; K = DIM; N = NQKV;
  } else {
    const int bb = b - 15040;
    bx = bb % 40; by = bb / 40; W = w_proj; T = wprojT; K = DIM; N = DIM;
  }
  const int tx = threadIdx.x & 31, ty = threadIdx.x >> 5;  // 32x8
  const int n0 = bx * 32, k0 = by * 32;
#pragma unroll
  for (int i = 0; i < 4; i++) {
    int r = ty + i * 8;
    tile[r][tx] = W[(size_t)(k0 + r) * N + n0 + tx];
  }
  __syncthreads();
#pragma unroll
  for (int i = 0; i < 4; i++) {
    int r = ty + i * 8;
    T[(size_t)(n0 + r) * K + k0 + tx] = f2bf(tile[tx][r]);
  }
}

// ---------------- mega tile (device fn): QKV GEMM + bias + RoPE + attention ----------------
// Verbatim transplant of the FROZEN mega_attn body (measured 131-134us over
// R3-R6 as a standalone kernel, MfmaUtil ~32), parameterized by (smem, n, h).
__device__ void mega_tile(char* smem, int n, int h,
                          const unsigned short* __restrict__ hb,
                          const unsigned short* __restrict__ wqkvT,
                          const float* __restrict__ b_qkv,
                          const float* __restrict__ cosb,
                          const float* __restrict__ sinb,
                          unsigned short* __restrict__ Ob) {
  unsigned short* X = (unsigned short*)smem;
  unsigned short* Y = (unsigned short*)(smem + 67584);
  unsigned short* Vt = (unsigned short*)(smem + 110592);  // [80][264]
  char* Abuf = smem;          // 4 x 16384
  char* Bbuf = smem + 65536;  // 4 x 16384

  const int t = threadIdx.x;
  const int lane = t & 63, w = t >> 6;
  const int lrow = lane & 15, lq = lane >> 4;
  const int s0 = n * 256;
  const int wm = w >> 1, wn = w & 1;

  // staging geometry (BK=32): per matrix 1024 16B-chunks/step (256 rows x 4 chunks);
  // stored pos p holds global chunk p ^ ((r>>1)&3) (XOR -> ~2-way banks on b128).
  const int tr2 = t >> 2;  // 0..127
  const int g8 = ((t & 3) ^ ((t >> 3) & 3)) * 8;
  const unsigned short* pA32[2];
  pA32[0] = hb + (size_t)(s0 + tr2) * 1280 + g8;
  pA32[1] = pA32[0] + (size_t)128 * 1280;
  const unsigned short* pB32[2];
#pragma unroll
  for (int i = 0; i < 2; i++) {
    const int r = tr2 + i * 128;
    const int rr = r < 240 ? r : 239;  // pad rows clamp (cols 240..255 never used)
    const int sgm = (rr >= 160) ? 2 : (rr >= 80 ? 1 : 0);
    pB32[i] = wqkvT + (size_t)(sgm * DIM + h * 80 + (rr - sgm * 80)) * 1280 + g8;
  }

  const int swzr = (lq ^ ((lrow >> 1) & 3)) * 16;
  int offA32[4], offB32[8];
#pragma unroll
  for (int i = 0; i < 4; i++) offA32[i] = (wm * 64 + i * 16 + lrow) * 64 + swzr;
#pragma unroll
  for (int j = 0; j < 8; j++) offB32[j] = (wn * 128 + j * 16 + lrow) * 64 + swzr;

  fx4 acc[4][8] = {};

  auto STAGE = [&](int k) {
    const int kof = k * 32;
    char* da = Abuf + (k & 3) * 16384 + w * 1024;
    char* db = Bbuf + (k & 3) * 16384 + w * 1024;
    gload_lds16(pA32[0] + kof, da);
    gload_lds16(pB32[0] + kof, db);
    gload_lds16(pA32[1] + kof, da + 8192);
    gload_lds16(pB32[1] + kof, db + 8192);
  };
  auto COMP = [&](int k) {
    const char* As = Abuf + (k & 3) * 16384;
    const char* Bs = Bbuf + (k & 3) * 16384;
    s16x8 a[4], b[8];
#pragma unroll
    for (int i = 0; i < 4; i++) a[i] = *(const s16x8*)(As + offA32[i]);
#pragma unroll
    for (int j = 0; j < 8; j++) b[j] = *(const s16x8*)(Bs + offB32[j]);
    __builtin_amdgcn_s_setprio(1);
#pragma unroll
    for (int i = 0; i < 4; i++)
#pragma unroll
      for (int j = 0; j < 8; j++)
        acc[i][j] = mfma16(a[i], b[j], acc[i][j]);
    __builtin_amdgcn_s_setprio(0);
  };

  // prologue: 3 K-steps in flight; counted vmcnt(8) keeps 2 bufs flying across
  // the barrier (T3/T4).
  STAGE(0); STAGE(1); STAGE(2);
  for (int k = 0; k < 38; k++) {
    asm volatile("s_waitcnt vmcnt(8)\n\ts_barrier" ::: "memory");
    if (k < 37) STAGE(k + 3);
    COMP(k);
  }
  asm volatile("s_waitcnt vmcnt(4)\n\ts_barrier" ::: "memory");
  COMP(38);
  asm volatile("s_waitcnt vmcnt(0)\n\ts_barrier" ::: "memory");
  COMP(39);
  __syncthreads();  // all fragment reads done before staging regions become Q/K/Vt

  // ---- epilogue scatter (branchless stride-select): acc + bias ->
  //      sgm 0/1: raw Q (Y) / K (X) @ row*84 + d; sgm 2: Vt transposed @ d*264 + row
#pragma unroll
  for (int j = 0; j < 8; j++) {
    const int col = wn * 128 + j * 16 + lrow;
    if (col < 240) {
      const int sgm = (col >= 160) ? 2 : (col >= 80 ? 1 : 0);
      const int d = col - sgm * 80;
      const float bv = b_qkv[sgm * DIM + h * 80 + d];
      unsigned short* dst = (sgm == 0) ? Y : (sgm == 1) ? X : Vt;
      const int rs = (sgm == 2) ? 1 : TS;
      const int dd = (sgm == 2) ? 264 : 1;
      const int dbase = d * dd;
#pragma unroll
      for (int i = 0; i < 4; i++) {
        const int row = wm * 64 + i * 16 + lq * 4;
#pragma unroll
        for (int r = 0; r < 4; r++)
          dst[(row + r) * rs + dbase] = f2bf(acc[i][j][r] + bv);
      }
    }
  }
  __syncthreads();  // B1: raw Q/K + Vt complete

  // ---- K rope -> regs; Q rope -> A-fragments ----
  unsigned short kout[5][8];
  int kro[5], kco[5];
#pragma unroll
  for (int i = 0; i < 5; i++) {
    const int idx = t + i * 512;
    const unsigned r = (unsigned)idx / 10u, c = (unsigned)idx % 10u;
    kro[i] = r; kco[i] = c;
    s16x8 xv = *(const s16x8*)&X[r * TS + c * 8];
    const unsigned cp = (c < 5) ? c + 5 : c - 5;  // partner chunk (+-40 elems)
    s16x8 pv = *(const s16x8*)&X[r * TS + cp * 8];
    const float sgn = (c < 5) ? -1.f : 1.f;
    const float* cf = cosb + (size_t)(s0 + r) * 80 + c * 8;
    const float* sf = sinb + (size_t)(s0 + r) * 80 + c * 8;
#pragma unroll
    for (int j = 0; j < 8; j++)
      kout[i][j] = f2bf(bf2f((unsigned short)xv[j]) * cf[j] +
                        sgn * bf2f((unsigned short)pv[j]) * sf[j]);
  }

  s16x8 aq[2][3];
#pragma unroll
  for (int rt = 0; rt < 2; rt++) {
#pragma unroll
    for (int c = 0; c < 3; c++) {
      const int row = w * 32 + rt * 16 + lrow;
      const int d0 = c * 32 + lq * 8;
      s16x8 fr = {};
      if (d0 < 80) {
        s16x8 xv = *(const s16x8*)&Y[row * TS + d0];
        const int dp = (d0 < 40) ? d0 + 40 : d0 - 40;
        s16x8 pv = *(const s16x8*)&Y[row * TS + dp];
        const float sgn = (d0 < 40) ? -1.f : 1.f;
        const float* cf = cosb + (size_t)(s0 + row) * 80 + d0;
        const float* sf = sinb + (size_t)(s0 + row) * 80 + d0;
#pragma unroll
        for (int j = 0; j < 8; j++)
          fr[j] = (short)f2bf(bf2f((unsigned short)xv[j]) * cf[j] +
                              sgn * bf2f((unsigned short)pv[j]) * sf[j]);
      }
      aq[rt][c] = fr;
    }
  }
  __syncthreads();  // B2: rawK/rawQ reads done

  // ---- write rope'd K at stride 104 + zero pad ----
#pragma unroll
  for (int i = 0; i < 5; i++)
    *(int4*)&X[kro[i] * 104 + kco[i] * 8] = *(const int4*)kout[i];
  {
    const int r = t >> 1, wh = t & 1;
    const int4 z = {0, 0, 0, 0};
    *(int4*)&X[r * 104 + 80 + wh * 8] = z;
  }
  __syncthreads();  // B3

  // ---- QK^T: 2 row-tiles x 16 col-tiles, K = 96 ----
  fx4 acc2[2][16] = {};
#pragma unroll
  for (int c = 0; c < 3; c++) {
#pragma unroll
    for (int ct = 0; ct < 16; ct++) {
      s16x8 b = *(const s16x8*)&X[(ct * 16 + lrow) * 104 + c * 32 + lq * 8];
      acc2[0][ct] = mfma16(aq[0][c], b, acc2[0][ct]);
      acc2[1][ct] = mfma16(aq[1][c], b, acc2[1][ct]);
    }
  }

  // ---- softmax (rows wave-local) ----
  const float kscale = 0.11180339887498949f * 1.4426950408889634f;  // 80^-0.5 * log2e
  float inv[2][4];
#pragma unroll
  for (int rt = 0; rt < 2; rt++) {
    float mx[4] = {-1e30f, -1e30f, -1e30f, -1e30f};
#pragma unroll
    for (int ct = 0; ct < 16; ct++)
#pragma unroll
      for (int r = 0; r < 4; r++) mx[r] = fmaxf(mx[r], acc2[rt][ct][r]);
#pragma unroll
    for (int r = 0; r < 4; r++) {
      mx[r] = fmaxf(mx[r], __shfl_xor(mx[r], 1));
      mx[r] = fmaxf(mx[r], __shfl_xor(mx[r], 2));
      mx[r] = fmaxf(mx[r], __shfl_xor(mx[r], 4));
      mx[r] = fmaxf(mx[r], __shfl_xor(mx[r], 8));
    }
    float sm[4] = {0.f, 0.f, 0.f, 0.f};
#pragma unroll
    for (int ct = 0; ct < 16; ct++)
#pragma unroll
      for (int r = 0; r < 4; r++) {
        float e = exp2f((acc2[rt][ct][r] - mx[r]) * kscale);
        acc2[rt][ct][r] = e;
        sm[r] += e;
      }
#pragma unroll
    for (int r = 0; r < 4; r++) {
      sm[r] += __shfl_xor(sm[r], 1);
      sm[r] += __shfl_xor(sm[r], 2);
      sm[r] += __shfl_xor(sm[r], 4);
      sm[r] += __shfl_xor(sm[r], 8);
      inv[rt][r] = 1.f / sm[r];
    }
  }
  __syncthreads();  // B4: Ks dead; X becomes per-wave P-scratch

  // ---- P (rt=0) to per-wave scratch (wave-private; Vt complete since B1) ----
  unsigned short* Pw = X + w * 4224;  // 16 rows x 264 elems
#pragma unroll
  for (int ct = 0; ct < 16; ct++)
#pragma unroll
    for (int r = 0; r < 4; r++)
      Pw[(lq * 4 + r) * 264 + ct * 16 + lrow] = f2bf(acc2[0][ct][r] * inv[0][r]);

  // ---- PV + output, two 16-row sweeps ----
#pragma unroll
  for (int rt = 0; rt < 2; rt++) {
    if (rt == 1) {
#pragma unroll
      for (int ct = 0; ct < 16; ct++)
#pragma unroll
        for (int r = 0; r < 4; r++)
          Pw[(lq * 4 + r) * 264 + ct * 16 + lrow] = f2bf(acc2[1][ct][r] * inv[1][r]);
    }
    fx4 accO[5] = {};
#pragma unroll
    for (int kc = 0; kc < 8; kc++) {
      s16x8 a = *(const s16x8*)&Pw[lrow * 264 + kc * 32 + lq * 8];
#pragma unroll
      for (int tt = 0; tt < 5; tt++) {
        s16x8 b = *(const s16x8*)&Vt[(tt * 16 + lrow) * 264 + kc * 32 + lq * 8];
        accO[tt] = mfma16(a, b, accO[tt]);
      }
    }
    const int srow = s0 + w * 32 + rt * 16 + lq * 4;
#pragma unroll
    for (int tt = 0; tt < 5; tt++) {
      const int col = h * 80 + tt * 16 + lrow;
#pragma unroll
      for (int r = 0; r < 4; r++)
        Ob[(size_t)(srow + r) * DIM + col] = f2bf(accO[tt][r]);
    }
  }
}

// ---------------- proj tile (device fn): 128x320, BK=64 dbuf ----------------
// Verbatim transplant of R6 gemm_proj body, parameterized by (smem, m0, n0).
__device__ void proj_tile(char* smem, int m0, int n0,
                          const unsigned short* __restrict__ A,
                          const unsigned short* __restrict__ Bt,
                          const float* __restrict__ bias,
                          float* __restrict__ C) {
  char* Abuf = smem;          // 2 x 16384
  char* Bbuf = smem + 32768;  // 2 x 40960

  const int t = threadIdx.x;
  const int lane = t & 63, w = t >> 6;
  const int lrow = lane & 15, lq = lane >> 4;
  const int l7 = lrow & 7;
  const int wm = w >> 2, wn = w & 3;  // 2x4 wave grid, per-wave 64x80 output

  const int tr3 = t >> 3;  // 0..63
  const int cch = ((t & 7) ^ (tr3 & 7)) * 8;
  const unsigned short* pA = A + (size_t)(m0 + tr3) * 1280 + cch;   // rows tr3, tr3+64
  const unsigned short* pB = Bt + (size_t)(n0 + tr3) * 1280 + cch;  // rows tr3 + i*64

  int offA[4][2], offB[5][2];
#pragma unroll
  for (int i = 0; i < 4; i++) {
    const int ra = wm * 64 + i * 16 + lrow;  // ra & 7 == l7
    offA[i][0] = ra * 128 + (lq ^ l7) * 16;
    offA[i][1] = ra * 128 + ((lq + 4) ^ l7) * 16;
  }
#pragma unroll
  for (int j = 0; j < 5; j++) {
    const int rb = wn * 80 + j * 16 + lrow;  // 80 % 8 == 0 -> rb & 7 == l7
    offB[j][0] = rb * 128 + (lq ^ l7) * 16;
    offB[j][1] = rb * 128 + ((lq + 4) ^ l7) * 16;
  }

  fx4 acc[4][5] = {};

  auto STAGE = [&](int k, int buf) {
    const int kof = k * 64;
    char* da = Abuf + buf * 16384 + w * 1024;
    char* db = Bbuf + buf * 40960 + w * 1024;
    gload_lds16(pA + kof, da);
    gload_lds16(pA + (size_t)64 * 1280 + kof, da + 8192);
#pragma unroll
    for (int i = 0; i < 5; i++)
      gload_lds16(pB + (size_t)i * 64 * 1280 + kof, db + i * 8192);
  };

  STAGE(0, 0);
  for (int k = 0; k < 20; k++) {
    asm volatile("s_waitcnt vmcnt(0)\n\ts_barrier" ::: "memory");
    if (k < 19) STAGE(k + 1, (k + 1) & 1);  // flies during compute(k)
    const char* As = Abuf + (k & 1) * 16384;
    const char* Bs = Bbuf + (k & 1) * 40960;
#pragma unroll
    for (int kq = 0; kq < 2; kq++) {
      s16x8 a[4], b[5];
#pragma unroll
      for (int i = 0; i < 4; i++) a[i] = *(const s16x8*)(As + offA[i][kq]);
#pragma unroll
      for (int j = 0; j < 5; j++) b[j] = *(const s16x8*)(Bs + offB[j][kq]);
      __builtin_amdgcn_s_setprio(1);
#pragma unroll
      for (int i = 0; i < 4; i++)
#pragma unroll
        for (int j = 0; j < 5; j++)
          acc[i][j] = mfma16(a[i], b[j], acc[i][j]);
      __builtin_amdgcn_s_setprio(0);
    }
  }

  // epilogue: acc + bias -> C (f32)
#pragma unroll
  for (int i = 0; i < 4; i++) {
    const int row_base = m0 + wm * 64 + i * 16 + lq * 4;
#pragma unroll
    for (int j = 0; j < 5; j++) {
      const int col = n0 + wn * 80 + j * 16 + lrow;
      const float bv = bias[col];
#pragma unroll
      for (int r = 0; r < 4; r++)
        C[(size_t)(row_base + r) * DIM + col] = acc[i][j][r] + bv;
    }
  }
}

// ---------------- fused cooperative kernel: 2x mega tile -> grid sync -> proj ----------------
// Grid 256 blocks x 512 thr = exactly 1 block/CU (LDS 153600 caps at 1 anyway),
// cooperative-launched. Physical block b runs mega tiles (n=b&31, h=b>>5) and
// (n, h+8) sequentially (same A-panel -> L2-hot second tile), then grid.sync()
// (device-scope: Ob globally visible), then proj tile (m0=(b>>2)*128, n0=(b&3)*320)
// at full CU coverage. Purpose: eliminates launch gaps AND makes the mega+proj
// total directly measurable as one dispatch (proj has never appeared in top-5;
// its true cost = this kernel's dur - ~132us from the frozen mega baseline).
__global__ __launch_bounds__(512, 2) void fused_mp(const unsigned short* __restrict__ hb,
                                                   const unsigned short* __restrict__ wqkvT,
                                                   const float* __restrict__ b_qkv,
                                                   const float* __restrict__ cosb,
                                                   const float* __restrict__ sinb,
                                                   unsigned short* __restrict__ Ob,
                                                   const unsigned short* __restrict__ wprojT,
                                                   const float* __restrict__ b_proj,
                                                   float* __restrict__ out) {
  __shared__ __attribute__((aligned(16))) char smem[153600];
  const int b = blockIdx.x;

  mega_tile(smem, b & 31, b >> 5, hb, wqkvT, b_qkv, cosb, sinb, Ob);
  __syncthreads();  // LDS reuse between tiles (PV reads done before re-staging)
  mega_tile(smem, b & 31, (b >> 5) + 8, hb, wqkvT, b_qkv, cosb, sinb, Ob);

  __threadfence();          // Ob stores device-visible (cross-XCD)
  cg::this_grid().sync();   // all mega tiles complete -> Ob fully written

  proj_tile(smem, (b >> 2) * 128, (b & 3) * 320, Ob, wprojT, b_proj, out);
}

// ---------------- launch ----------------
extern "C" void kernel_launch(void* const* d_in, const int* in_sizes, int n_in,
                              void* d_out, int out_size, void* d_ws, size_t ws_size,
                              hipStream_t stream) {
  const float* hidden = (const float*)d_in[0];
  // d_in[1] = cu_seqlens: fixed layout (32 chunks of 256), unused
  const float* cosb = (const float*)d_in[2];
  const float* sinb = (const float*)d_in[3];
  const float* w_qkv = (const float*)d_in[4];
  const float* b_qkv = (const float*)d_in[5];
  const float* w_proj = (const float*)d_in[6];
  const float* b_proj = (const float*)d_in[7];
  float* out = (float*)d_out;

  // workspace layout (bytes)
  char* ws = (char*)d_ws;
  constexpr size_t HB_B = (size_t)SEQ * DIM * 2;    // 20,971,520 hidden bf16
  constexpr size_t WQT_B = (size_t)NQKV * DIM * 2;  //  9,830,400 w_qkv^T bf16
  constexpr size_t WPT_B = (size_t)DIM * DIM * 2;   //  3,276,800 w_proj^T bf16
  constexpr size_t OB_B = (size_t)SEQ * DIM * 2;    // 20,971,520 attn out bf16
  size_t off = 0;
  unsigned short* hb = (unsigned short*)(ws + off);     off += HB_B;
  unsigned short* wqkvT = (unsigned short*)(ws + off);  off += WQT_B;
  unsigned short* wprojT = (unsigned short*)(ws + off); off += WPT_B;
  unsigned short* Ob = (unsigned short*)(ws + off);     off += OB_B;
  if (ws_size < off) return;

  // 1. fused prep: cast hidden + transpose-cast w_qkv/w_proj (one launch)
  prep_kernel<<<dim3(16640), dim3(256), 0, stream>>>(hidden, hb, w_qkv, wqkvT,
                                                     w_proj, wprojT);

  // 2. fused cooperative mega+proj (grid 256 = 1 block/CU, co-resident)
  void* args[] = {(void*)&hb, (void*)&wqkvT, (void*)&b_qkv, (void*)&cosb,
                  (void*)&sinb, (void*)&Ob, (void*)&wprojT, (void*)&b_proj,
                  (void*)&out};
  hipLaunchCooperativeKernel((const void*)fused_mp, dim3(256), dim3(512), args, 0,
                             stream);
}

// Round 8
// 301.165 us; speedup vs baseline: 1.3726x; 1.3726x over previous
//
#include <hip/hip_runtime.h>
#include <stdint.h>

#define DEVFN __device__ __forceinline__

typedef short s16x8 __attribute__((ext_vector_type(8)));
typedef __bf16 bf16x8 __attribute__((ext_vector_type(8)));
typedef float fx4 __attribute__((ext_vector_type(4)));

// Problem constants (fixed by the reference)
constexpr int SEQ = 8192, DIM = 1280, HEADS = 16;
constexpr int NIMG = 32;
constexpr int NQKV = 3840;  // 3*DIM
constexpr int TS = 84;      // raw Q/K tile stride (168B rows: scatter = 2 lanes/bank, free)

DEVFN unsigned short f2bf(float f) {
  union { float f; unsigned u; } v; v.f = f;
  unsigned r = v.u + 0x7FFFu + ((v.u >> 16) & 1u);  // RNE
  return (unsigned short)(r >> 16);
}
DEVFN float bf2f(unsigned short u) {
  union { unsigned u; float f; } v; v.u = ((unsigned)u) << 16;
  return v.f;
}

DEVFN fx4 mfma16(s16x8 a, s16x8 b, fx4 c) {
  return __builtin_amdgcn_mfma_f32_16x16x32_bf16(
      __builtin_bit_cast(bf16x8, a), __builtin_bit_cast(bf16x8, b), c, 0, 0, 0);
}

DEVFN void gload_lds16(const void* g, void* l) {
  // global -> LDS direct, 16B per lane; LDS dest = wave-uniform base + lane*16
  __builtin_amdgcn_global_load_lds(
      (__attribute__((address_space(1))) void*)(uintptr_t)g,
      (__attribute__((address_space(3))) void*)l, 16, 0, 0);
}

// ---------------- fused prep: cast hidden + transpose-cast both weights ----------------
__global__ __launch_bounds__(256) void prep_kernel(const float* __restrict__ hidden,
                                                   unsigned short* __restrict__ hb,
                                                   const float* __restrict__ w_qkv,
                                                   unsigned short* __restrict__ wqkvT,
                                                   const float* __restrict__ w_proj,
                                                   unsigned short* __restrict__ wprojT) {
  const int b = blockIdx.x;
  if (b < 10240) {  // cast: 10240*256*4 = SEQ*DIM exactly
    const int i = b * 256 + threadIdx.x;
    float4 v = ((const float4*)hidden)[i];
    ushort4 o;
    o.x = f2bf(v.x); o.y = f2bf(v.y); o.z = f2bf(v.z); o.w = f2bf(v.w);
    ((ushort4*)hb)[i] = o;
    return;
  }
  __shared__ float tile[32][33];
  const float* W; unsigned short* T;
  int K, N, bx, by;
  if (b < 15040) {
    const int bb = b - 10240;
    bx = bb % 120; by = bb / 120; W = w_qkv; T = wqkvT; K = DIM; N = NQKV;
  } else {
    const int bb = b - 15040;
    bx = bb % 40; by = bb / 40; W = w_proj; T = wprojT; K = DIM; N = DIM;
  }
  const int tx = threadIdx.x & 31, ty = threadIdx.x >> 5;  // 32x8
  const int n0 = bx * 32, k0 = by * 32;
#pragma unroll
  for (int i = 0; i < 4; i++) {
    int r = ty + i * 8;
    tile[r][tx] = W[(size_t)(k0 + r) * N + n0 + tx];
  }
  __syncthreads();
#pragma unroll
  for (int i = 0; i < 4; i++) {
    int r = ty + i * 8;
    T[(size_t)(n0 + r) * K + k0 + tx] = f2bf(tile[tx][r]);
  }
}

// ---------------- mega kernel: QKV GEMM + bias + RoPE + attention, 16 WAVES ----------------
// R8 restructure: 1024 threads = 16 waves, 1 block/CU -> 4 waves/SIMD (was 2).
// Occupancy was the theory-identified stall multiplier (R7 decomposition: mega=132us
// is 2.6x its issue-bound estimate; Occupancy 21%). Halved per-wave register state:
// GEMM wave grid 4x4 (acc[4][4]=64f), attention 16 q-rows/wave (acc2[16]=64f) ->
// target <=128 unified VGPR (launch_bounds(1024,4)). P-scratch (131KB > X's 67.5KB)
// split into even-wave/odd-wave PV phases sharing X. GEMM: BK=32 quad ring, depth-3
// prefetch, counted vmcnt (2 loads/thread/step -> 4/2/0), setprio. Epilogue scatter
// and attention math transplanted from the R3-R6 frozen kernel (same formulas; only
// wave-ownership re-indexed). LDS unchanged 153600 B.
__global__ __launch_bounds__(1024, 4) void mega_attn(const unsigned short* __restrict__ hb,
                                                     const unsigned short* __restrict__ wqkvT,
                                                     const float* __restrict__ b_qkv,
                                                     const float* __restrict__ cosb,
                                                     const float* __restrict__ sinb,
                                                     unsigned short* __restrict__ Ob) {
  __shared__ __attribute__((aligned(16))) char smem[153600];
  unsigned short* X = (unsigned short*)smem;
  unsigned short* Y = (unsigned short*)(smem + 67584);
  unsigned short* Vt = (unsigned short*)(smem + 110592);  // [80][264]
  char* Abuf = smem;          // 4 x 16384
  char* Bbuf = smem + 65536;  // 4 x 16384

  const int t = threadIdx.x;
  const int lane = t & 63, w = t >> 6;       // 16 waves
  const int lrow = lane & 15, lq = lane >> 4;
  const int n = blockIdx.x, h = blockIdx.y;
  const int s0 = n * 256;
  const int wm = w >> 2, wn = w & 3;         // 4x4 wave grid, 64x64 out per wave

  // staging geometry (BK=32): per matrix 1024 16B-chunks/step; thread covers slot t.
  // slot t -> row r = t>>2, pos p = t&3; stored pos p holds global chunk
  // p ^ ((r>>1)&3) = (t&3)^((t>>3)&3)  (XOR -> ~2-way banks on ds_read_b128).
  const int tr2 = t >> 2;  // 0..255
  const int g8 = ((t & 3) ^ ((t >> 3) & 3)) * 8;
  const unsigned short* pA32 = hb + (size_t)(s0 + tr2) * 1280 + g8;
  const unsigned short* pB32;
  {
    const int rr = tr2 < 240 ? tr2 : 239;  // pad rows clamp (cols 240..255 unused)
    const int sgm = (rr >= 160) ? 2 : (rr >= 80 ? 1 : 0);
    pB32 = wqkvT + (size_t)(sgm * DIM + h * 80 + (rr - sgm * 80)) * 1280 + g8;
  }

  // fragment read offsets: row ra, stored chunk lq ^ ((ra>>1)&3); (ra>>1)&3 == (lrow>>1)&3.
  const int swzr = (lq ^ ((lrow >> 1) & 3)) * 16;
  int offA32[4], offB32[4];
#pragma unroll
  for (int i = 0; i < 4; i++) {
    offA32[i] = (wm * 64 + i * 16 + lrow) * 64 + swzr;
    offB32[i] = (wn * 64 + i * 16 + lrow) * 64 + swzr;
  }

  fx4 acc[4][4] = {};

  auto STAGE = [&](int k) {
    const int kof = k * 32;
    gload_lds16(pA32 + kof, Abuf + (k & 3) * 16384 + w * 1024);
    gload_lds16(pB32 + kof, Bbuf + (k & 3) * 16384 + w * 1024);
  };
  auto COMP = [&](int k) {
    const char* As = Abuf + (k & 3) * 16384;
    const char* Bs = Bbuf + (k & 3) * 16384;
    s16x8 a[4], b[4];
#pragma unroll
    for (int i = 0; i < 4; i++) a[i] = *(const s16x8*)(As + offA32[i]);
#pragma unroll
    for (int j = 0; j < 4; j++) b[j] = *(const s16x8*)(Bs + offB32[j]);
    __builtin_amdgcn_s_setprio(1);
#pragma unroll
    for (int i = 0; i < 4; i++)
#pragma unroll
      for (int j = 0; j < 4; j++)
        acc[i][j] = mfma16(a[i], b[j], acc[i][j]);
    __builtin_amdgcn_s_setprio(0);
  };

  // prologue: 3 K-steps in flight (6 loads/thread); counted vmcnt keeps 2 bufs
  // flying across the barrier (T3/T4). 2 loads/step -> waits 4/2/0.
  STAGE(0); STAGE(1); STAGE(2);
  for (int k = 0; k < 38; k++) {
    asm volatile("s_waitcnt vmcnt(4)\n\ts_barrier" ::: "memory");
    if (k < 37) STAGE(k + 3);
    COMP(k);
  }
  asm volatile("s_waitcnt vmcnt(2)\n\ts_barrier" ::: "memory");
  COMP(38);
  asm volatile("s_waitcnt vmcnt(0)\n\ts_barrier" ::: "memory");
  COMP(39);
  __syncthreads();  // all fragment reads done before staging regions become Q/K/Vt

  // ---- epilogue scatter (branchless stride-select): acc + bias ->
  //      sgm 0/1: raw Q (Y) / K (X) @ row*84 + d; sgm 2: Vt transposed @ d*264 + row
#pragma unroll
  for (int j = 0; j < 4; j++) {
    const int col = wn * 64 + j * 16 + lrow;
    if (col < 240) {
      const int sgm = (col >= 160) ? 2 : (col >= 80 ? 1 : 0);
      const int d = col - sgm * 80;
      const float bv = b_qkv[sgm * DIM + h * 80 + d];
      unsigned short* dst = (sgm == 0) ? Y : (sgm == 1) ? X : Vt;
      const int rs = (sgm == 2) ? 1 : TS;
      const int dd = (sgm == 2) ? 264 : 1;
      const int dbase = d * dd;
#pragma unroll
      for (int i = 0; i < 4; i++) {
        const int row = wm * 64 + i * 16 + lq * 4;
#pragma unroll
        for (int r = 0; r < 4; r++)
          dst[(row + r) * rs + dbase] = f2bf(acc[i][j][r] + bv);
      }
    }
  }
  __syncthreads();  // B1: raw Q/K + Vt complete

  // ---- K rope -> regs (2560 items over 1024 threads, 3 strided iters) ----
  unsigned short kout[3][8];
  int kro[3], kco[3];
#pragma unroll
  for (int i = 0; i < 3; i++) {
    const int idx = t + i * 1024;
    if (idx < 2560) {
      const unsigned r = (unsigned)idx / 10u, c = (unsigned)idx % 10u;
      kro[i] = r; kco[i] = c;
      s16x8 xv = *(const s16x8*)&X[r * TS + c * 8];
      const unsigned cp = (c < 5) ? c + 5 : c - 5;  // partner chunk (+-40 elems)
      s16x8 pv = *(const s16x8*)&X[r * TS + cp * 8];
      const float sgn = (c < 5) ? -1.f : 1.f;
      const float* cf = cosb + (size_t)(s0 + r) * 80 + c * 8;
      const float* sf = sinb + (size_t)(s0 + r) * 80 + c * 8;
#pragma unroll
      for (int j = 0; j < 8; j++)
        kout[i][j] = f2bf(bf2f((unsigned short)xv[j]) * cf[j] +
                          sgn * bf2f((unsigned short)pv[j]) * sf[j]);
    } else {
      kro[i] = -1;
    }
  }

  // ---- Q rope -> A-fragments (wave w owns q-rows w*16..w*16+15) ----
  s16x8 aq[3];
#pragma unroll
  for (int c = 0; c < 3; c++) {
    const int row = w * 16 + lrow;
    const int d0 = c * 32 + lq * 8;
    s16x8 fr = {};
    if (d0 < 80) {
      s16x8 xv = *(const s16x8*)&Y[row * TS + d0];
      const int dp = (d0 < 40) ? d0 + 40 : d0 - 40;
      s16x8 pv = *(const s16x8*)&Y[row * TS + dp];
      const float sgn = (d0 < 40) ? -1.f : 1.f;
      const float* cf = cosb + (size_t)(s0 + row) * 80 + d0;
      const float* sf = sinb + (size_t)(s0 + row) * 80 + d0;
#pragma unroll
      for (int j = 0; j < 8; j++)
        fr[j] = (short)f2bf(bf2f((unsigned short)xv[j]) * cf[j] +
                            sgn * bf2f((unsigned short)pv[j]) * sf[j]);
    }
    aq[c] = fr;
  }
  __syncthreads();  // B2: rawK/rawQ reads done

  // ---- write rope'd K at stride 104 + zero pad (t<512: rows t>>1, 2 chunks) ----
#pragma unroll
  for (int i = 0; i < 3; i++)
    if (kro[i] >= 0)
      *(int4*)&X[kro[i] * 104 + kco[i] * 8] = *(const int4*)kout[i];
  if (t < 512) {
    const int r = t >> 1, wh = t & 1;
    const int4 z = {0, 0, 0, 0};
    *(int4*)&X[r * 104 + 80 + wh * 8] = z;
  }
  __syncthreads();  // B3

  // ---- QK^T: 16 col-tiles, K = 96 ----
  fx4 acc2[16] = {};
#pragma unroll
  for (int c = 0; c < 3; c++) {
#pragma unroll
    for (int ct = 0; ct < 16; ct++) {
      s16x8 b = *(const s16x8*)&X[(ct * 16 + lrow) * 104 + c * 32 + lq * 8];
      acc2[ct] = mfma16(aq[c], b, acc2[ct]);
    }
  }

  // ---- softmax (rows wave-local: row = lq*4 + r of this wave's 16) ----
  const float kscale = 0.11180339887498949f * 1.4426950408889634f;  // 80^-0.5 * log2e
  float inv[4];
  {
    float mx[4] = {-1e30f, -1e30f, -1e30f, -1e30f};
#pragma unroll
    for (int ct = 0; ct < 16; ct++)
#pragma unroll
      for (int r = 0; r < 4; r++) mx[r] = fmaxf(mx[r], acc2[ct][r]);
#pragma unroll
    for (int r = 0; r < 4; r++) {
      mx[r] = fmaxf(mx[r], __shfl_xor(mx[r], 1));
      mx[r] = fmaxf(mx[r], __shfl_xor(mx[r], 2));
      mx[r] = fmaxf(mx[r], __shfl_xor(mx[r], 4));
      mx[r] = fmaxf(mx[r], __shfl_xor(mx[r], 8));
    }
    float sm[4] = {0.f, 0.f, 0.f, 0.f};
#pragma unroll
    for (int ct = 0; ct < 16; ct++)
#pragma unroll
      for (int r = 0; r < 4; r++) {
        float e = exp2f((acc2[ct][r] - mx[r]) * kscale);
        acc2[ct][r] = e;
        sm[r] += e;
      }
#pragma unroll
    for (int r = 0; r < 4; r++) {
      sm[r] += __shfl_xor(sm[r], 1);
      sm[r] += __shfl_xor(sm[r], 2);
      sm[r] += __shfl_xor(sm[r], 4);
      sm[r] += __shfl_xor(sm[r], 8);
      inv[r] = 1.f / sm[r];
    }
  }
  __syncthreads();  // B4: Ks dead; X becomes P-scratch (8 wave-regions x 4224 elems)

  // ---- P + PV + output, two wave-phases sharing the 67.5KB X region ----
  auto PVOUT = [&](int wp) {
    unsigned short* Pw = X + wp * 4224;  // 16 rows x 264 elems
#pragma unroll
    for (int ct = 0; ct < 16; ct++)
#pragma unroll
      for (int r = 0; r < 4; r++)
        Pw[(lq * 4 + r) * 264 + ct * 16 + lrow] = f2bf(acc2[ct][r] * inv[r]);
    fx4 accO[5] = {};
#pragma unroll
    for (int kc = 0; kc < 8; kc++) {
      s16x8 a = *(const s16x8*)&Pw[lrow * 264 + kc * 32 + lq * 8];
#pragma unroll
      for (int tt = 0; tt < 5; tt++) {
        s16x8 b = *(const s16x8*)&Vt[(tt * 16 + lrow) * 264 + kc * 32 + lq * 8];
        accO[tt] = mfma16(a, b, accO[tt]);
      }
    }
    const int srow = s0 + w * 16 + lq * 4;
#pragma unroll
    for (int tt = 0; tt < 5; tt++) {
      const int col = h * 80 + tt * 16 + lrow;
#pragma unroll
      for (int r = 0; r < 4; r++)
        Ob[(size_t)(srow + r) * DIM + col] = f2bf(accO[tt][r]);
    }
  };
  if (w < 8) PVOUT(w);
  __syncthreads();  // phase A PV reads done before phase B overwrites X
  if (w >= 8) PVOUT(w - 8);
}

// ---------------- proj GEMM: 128x320 tile, BK=64 dbuf, grid 256 = 1 block/CU ----------------
// R6-measured (~20us by the R7 decomposition). Proven vmcnt(0) dbuf schedule;
// 8 waves (2M x 4N), per-wave 64x80 -> 40 MFMA per K-step. XOR-8 swizzle staging.
// LDS 112 KB: As 2x16K @0, Bs 2x40K @32768.
__global__ __launch_bounds__(512, 2) void gemm_proj(const unsigned short* __restrict__ A,
                                                    const unsigned short* __restrict__ Bt,
                                                    const float* __restrict__ bias,
                                                    float* __restrict__ C) {
  __shared__ __attribute__((aligned(16))) char smem[114688];
  char* Abuf = smem;          // 2 x 16384
  char* Bbuf = smem + 32768;  // 2 x 40960

  const int t = threadIdx.x;
  const int lane = t & 63, w = t >> 6;
  const int lrow = lane & 15, lq = lane >> 4;
  const int l7 = lrow & 7;
  const int wm = w >> 2, wn = w & 3;  // 2x4 wave grid, per-wave 64x80 output
  const int m0 = blockIdx.x * 128, n0 = blockIdx.y * 320;

  const int tr3 = t >> 3;  // 0..63
  const int cch = ((t & 7) ^ (tr3 & 7)) * 8;
  const unsigned short* pA = A + (size_t)(m0 + tr3) * 1280 + cch;   // rows tr3, tr3+64
  const unsigned short* pB = Bt + (size_t)(n0 + tr3) * 1280 + cch;  // rows tr3 + i*64

  int offA[4][2], offB[5][2];
#pragma unroll
  for (int i = 0; i < 4; i++) {
    const int ra = wm * 64 + i * 16 + lrow;  // ra & 7 == l7
    offA[i][0] = ra * 128 + (lq ^ l7) * 16;
    offA[i][1] = ra * 128 + ((lq + 4) ^ l7) * 16;
  }
#pragma unroll
  for (int j = 0; j < 5; j++) {
    const int rb = wn * 80 + j * 16 + lrow;  // 80 % 8 == 0 -> rb & 7 == l7
    offB[j][0] = rb * 128 + (lq ^ l7) * 16;
    offB[j][1] = rb * 128 + ((lq + 4) ^ l7) * 16;
  }

  fx4 acc[4][5] = {};

  auto STAGE = [&](int k, int buf) {
    const int kof = k * 64;
    char* da = Abuf + buf * 16384 + w * 1024;
    char* db = Bbuf + buf * 40960 + w * 1024;
    gload_lds16(pA + kof, da);
    gload_lds16(pA + (size_t)64 * 1280 + kof, da + 8192);
#pragma unroll
    for (int i = 0; i < 5; i++)
      gload_lds16(pB + (size_t)i * 64 * 1280 + kof, db + i * 8192);
  };

  STAGE(0, 0);
  for (int k = 0; k < 20; k++) {
    asm volatile("s_waitcnt vmcnt(0)\n\ts_barrier" ::: "memory");
    if (k < 19) STAGE(k + 1, (k + 1) & 1);  // flies during compute(k)
    const char* As = Abuf + (k & 1) * 16384;
    const char* Bs = Bbuf + (k & 1) * 40960;
#pragma unroll
    for (int kq = 0; kq < 2; kq++) {
      s16x8 a[4], b[5];
#pragma unroll
      for (int i = 0; i < 4; i++) a[i] = *(const s16x8*)(As + offA[i][kq]);
#pragma unroll
      for (int j = 0; j < 5; j++) b[j] = *(const s16x8*)(Bs + offB[j][kq]);
      __builtin_amdgcn_s_setprio(1);
#pragma unroll
      for (int i = 0; i < 4; i++)
#pragma unroll
        for (int j = 0; j < 5; j++)
          acc[i][j] = mfma16(a[i], b[j], acc[i][j]);
      __builtin_amdgcn_s_setprio(0);
    }
  }

  // epilogue: acc + bias -> C (f32)
#pragma unroll
  for (int i = 0; i < 4; i++) {
    const int row_base = m0 + wm * 64 + i * 16 + lq * 4;
#pragma unroll
    for (int j = 0; j < 5; j++) {
      const int col = n0 + wn * 80 + j * 16 + lrow;
      const float bv = bias[col];
#pragma unroll
      for (int r = 0; r < 4; r++)
        C[(size_t)(row_base + r) * DIM + col] = acc[i][j][r] + bv;
    }
  }
}

// ---------------- launch ----------------
extern "C" void kernel_launch(void* const* d_in, const int* in_sizes, int n_in,
                              void* d_out, int out_size, void* d_ws, size_t ws_size,
                              hipStream_t stream) {
  const float* hidden = (const float*)d_in[0];
  // d_in[1] = cu_seqlens: fixed layout (32 chunks of 256), unused
  const float* cosb = (const float*)d_in[2];
  const float* sinb = (const float*)d_in[3];
  const float* w_qkv = (const float*)d_in[4];
  const float* b_qkv = (const float*)d_in[5];
  const float* w_proj = (const float*)d_in[6];
  const float* b_proj = (const float*)d_in[7];
  float* out = (float*)d_out;

  // workspace layout (bytes)
  char* ws = (char*)d_ws;
  constexpr size_t HB_B = (size_t)SEQ * DIM * 2;    // 20,971,520 hidden bf16
  constexpr size_t WQT_B = (size_t)NQKV * DIM * 2;  //  9,830,400 w_qkv^T bf16
  constexpr size_t WPT_B = (size_t)DIM * DIM * 2;   //  3,276,800 w_proj^T bf16
  constexpr size_t OB_B = (size_t)SEQ * DIM * 2;    // 20,971,520 attn out bf16
  size_t off = 0;
  unsigned short* hb = (unsigned short*)(ws + off);     off += HB_B;
  unsigned short* wqkvT = (unsigned short*)(ws + off);  off += WQT_B;
  unsigned short* wprojT = (unsigned short*)(ws + off); off += WPT_B;
  unsigned short* Ob = (unsigned short*)(ws + off);     off += OB_B;
  if (ws_size < off) return;

  // 1. fused prep: cast hidden + transpose-cast w_qkv/w_proj (one launch)
  prep_kernel<<<dim3(16640), dim3(256), 0, stream>>>(hidden, hb, w_qkv, wqkvT,
                                                     w_proj, wprojT);
  // 2. mega: QKV GEMM + RoPE + attention -> Ob (16-wave, 4 waves/SIMD)
  mega_attn<<<dim3(NIMG, HEADS), dim3(1024), 0, stream>>>(hb, wqkvT, b_qkv, cosb, sinb, Ob);
  // 3. proj GEMM (+bias) -> d_out (f32), 128x320 tiles, grid 256
  gemm_proj<<<dim3(SEQ / 128, DIM / 320), dim3(512), 0, stream>>>(
      Ob, wprojT, b_proj, out);
}

// Round 9
// 270.771 us; speedup vs baseline: 1.5266x; 1.1122x over previous
//
#include <hip/hip_runtime.h>
#include <stdint.h>

#define DEVFN __device__ __forceinline__

typedef short s16x8 __attribute__((ext_vector_type(8)));
typedef __bf16 bf16x8 __attribute__((ext_vector_type(8)));
typedef float fx4 __attribute__((ext_vector_type(4)));

// Problem constants (fixed by the reference)
constexpr int SEQ = 8192, DIM = 1280, HEADS = 16;
constexpr int NIMG = 32;
constexpr int NQKV = 3840;  // 3*DIM
constexpr int TS = 84;      // raw Q/K tile stride (168B rows: scatter = 2 lanes/bank, free)

DEVFN unsigned short f2bf(float f) {
  union { float f; unsigned u; } v; v.f = f;
  unsigned r = v.u + 0x7FFFu + ((v.u >> 16) & 1u);  // RNE
  return (unsigned short)(r >> 16);
}
DEVFN float bf2f(unsigned short u) {
  union { unsigned u; float f; } v; v.u = ((unsigned)u) << 16;
  return v.f;
}

DEVFN fx4 mfma16(s16x8 a, s16x8 b, fx4 c) {
  return __builtin_amdgcn_mfma_f32_16x16x32_bf16(
      __builtin_bit_cast(bf16x8, a), __builtin_bit_cast(bf16x8, b), c, 0, 0, 0);
}

DEVFN void gload_lds16(const void* g, void* l) {
  // global -> LDS direct, 16B per lane; LDS dest = wave-uniform base + lane*16
  __builtin_amdgcn_global_load_lds(
      (__attribute__((address_space(1))) void*)(uintptr_t)g,
      (__attribute__((address_space(3))) void*)l, 16, 0, 0);
}

// ---------------- fused prep: cast hidden + transpose-cast both weights ----------------
__global__ __launch_bounds__(256) void prep_kernel(const float* __restrict__ hidden,
                                                   unsigned short* __restrict__ hb,
                                                   const float* __restrict__ w_qkv,
                                                   unsigned short* __restrict__ wqkvT,
                                                   const float* __restrict__ w_proj,
                                                   unsigned short* __restrict__ wprojT) {
  const int b = blockIdx.x;
  if (b < 10240) {  // cast: 10240*256*4 = SEQ*DIM exactly
    const int i = b * 256 + threadIdx.x;
    float4 v = ((const float4*)hidden)[i];
    ushort4 o;
    o.x = f2bf(v.x); o.y = f2bf(v.y); o.z = f2bf(v.z); o.w = f2bf(v.w);
    ((ushort4*)hb)[i] = o;
    return;
  }
  __shared__ float tile[32][33];
  const float* W; unsigned short* T;
  int K, N, bx, by;
  if (b < 15040) {
    const int bb = b - 10240;
    bx = bb % 120; by = bb / 120; W = w_qkv; T = wqkvT; K = DIM; N = NQKV;
  } else {
    const int bb = b - 15040;
    bx = bb % 40; by = bb / 40; W = w_proj; T = wprojT; K = DIM; N = DIM;
  }
  const int tx = threadIdx.x & 31, ty = threadIdx.x >> 5;  // 32x8
  const int n0 = bx * 32, k0 = by * 32;
#pragma unroll
  for (int i = 0; i < 4; i++) {
    int r = ty + i * 8;
    tile[r][tx] = W[(size_t)(k0 + r) * N + n0 + tx];
  }
  __syncthreads();
#pragma unroll
  for (int i = 0; i < 4; i++) {
    int r = ty + i * 8;
    T[(size_t)(n0 + r) * K + k0 + tx] = f2bf(tile[tx][r]);
  }
}

// ---------------- mega kernel: QKV GEMM + bias + RoPE + attention ----------------
// R9: reverted to the 8-wave R3-R6 frozen structure (R8's 16-wave occupancy
// experiment regressed 132->152: schedule-bound, not wave-starved). ONE change vs
// R6: each K-step's COMP is split into two phase-clusters in the m201 8-phase style
// {ds-read burst; lgkmcnt(0); setprio'd 16-MFMA cluster; s_barrier; second burst;
// 16-MFMA}. The quad-ring staging + counted vmcnt(8) skeleton is untouched; the
// added mid-step barrier is pure alignment (buf k complete before the step; staging
// targets a different ring slot) -> no new data hazards.
// Block = (img n, head h), 512 threads = 8 waves (4x2). GEMM: 256x256x1280, BK=32.
// LDS (153600 B): ring Abuf 4x16K @0, Bbuf 4x16K @65536 (dead after K-loop);
// X@0 (rawK84 -> Ks[256][104] -> P-scratch 8x16x264), Y@67584 (rawQ84),
// Vt@110592 (80x264).
__global__ __launch_bounds__(512, 2) void mega_attn(const unsigned short* __restrict__ hb,
                                                    const unsigned short* __restrict__ wqkvT,
                                                    const float* __restrict__ b_qkv,
                                                    const float* __restrict__ cosb,
                                                    const float* __restrict__ sinb,
                                                    unsigned short* __restrict__ Ob) {
  __shared__ __attribute__((aligned(16))) char smem[153600];
  unsigned short* X = (unsigned short*)smem;
  unsigned short* Y = (unsigned short*)(smem + 67584);
  unsigned short* Vt = (unsigned short*)(smem + 110592);  // [80][264]
  char* Abuf = smem;          // 4 x 16384
  char* Bbuf = smem + 65536;  // 4 x 16384

  const int t = threadIdx.x;
  const int lane = t & 63, w = t >> 6;
  const int lrow = lane & 15, lq = lane >> 4;
  const int n = blockIdx.x, h = blockIdx.y;
  const int s0 = n * 256;
  const int wm = w >> 1, wn = w & 1;

  // staging geometry (BK=32): per matrix 1024 16B-chunks/step (256 rows x 4 chunks);
  // thread covers slots t and t+512. slot s -> row r = s>>2, pos p = s&3; stored pos p
  // holds global chunk p ^ ((r>>1)&3)  (swizzle -> ~2-way banks on ds_read_b128).
  const int tr2 = t >> 2;  // 0..127
  const int g8 = ((t & 3) ^ ((t >> 3) & 3)) * 8;
  const unsigned short* pA32[2];
  pA32[0] = hb + (size_t)(s0 + tr2) * 1280 + g8;
  pA32[1] = pA32[0] + (size_t)128 * 1280;
  const unsigned short* pB32[2];
#pragma unroll
  for (int i = 0; i < 2; i++) {
    const int r = tr2 + i * 128;
    const int rr = r < 240 ? r : 239;  // pad rows clamp (cols 240..255 never used)
    const int sgm = (rr >= 160) ? 2 : (rr >= 80 ? 1 : 0);
    pB32[i] = wqkvT + (size_t)(sgm * DIM + h * 80 + (rr - sgm * 80)) * 1280 + g8;
  }

  // fragment read offsets: row ra, chunk lq ^ ((ra>>1)&3); (ra>>1)&3 == (lrow>>1)&3.
  const int swzr = (lq ^ ((lrow >> 1) & 3)) * 16;
  int offA32[4], offB32[8];
#pragma unroll
  for (int i = 0; i < 4; i++) offA32[i] = (wm * 64 + i * 16 + lrow) * 64 + swzr;
#pragma unroll
  for (int j = 0; j < 8; j++) offB32[j] = (wn * 128 + j * 16 + lrow) * 64 + swzr;

  fx4 acc[4][8] = {};

  auto STAGE = [&](int k) {
    const int kof = k * 32;
    char* da = Abuf + (k & 3) * 16384 + w * 1024;
    char* db = Bbuf + (k & 3) * 16384 + w * 1024;
    gload_lds16(pA32[0] + kof, da);
    gload_lds16(pB32[0] + kof, db);
    gload_lds16(pA32[1] + kof, da + 8192);
    gload_lds16(pB32[1] + kof, db + 8192);
  };
  // Two-phase clustered compute (m201-style): burst ds_reads, drain lgkm, protected
  // MFMA cluster, alignment barrier, second burst + cluster.
  auto COMP = [&](int k) {
    const char* As = Abuf + (k & 3) * 16384;
    const char* Bs = Bbuf + (k & 3) * 16384;
    s16x8 a[4], b0[4], b1[4];
#pragma unroll
    for (int i = 0; i < 4; i++) a[i] = *(const s16x8*)(As + offA32[i]);
#pragma unroll
    for (int j = 0; j < 4; j++) b0[j] = *(const s16x8*)(Bs + offB32[j]);
    asm volatile("s_waitcnt lgkmcnt(0)" ::: "memory");
    __builtin_amdgcn_sched_barrier(0);
    __builtin_amdgcn_s_setprio(1);
#pragma unroll
    for (int i = 0; i < 4; i++)
#pragma unroll
      for (int j = 0; j < 4; j++)
        acc[i][j] = mfma16(a[i], b0[j], acc[i][j]);
    __builtin_amdgcn_s_setprio(0);
    __builtin_amdgcn_s_barrier();  // alignment only: no data handoff at this barrier
#pragma unroll
    for (int j = 0; j < 4; j++) b1[j] = *(const s16x8*)(Bs + offB32[j + 4]);
    asm volatile("s_waitcnt lgkmcnt(0)" ::: "memory");
    __builtin_amdgcn_sched_barrier(0);
    __builtin_amdgcn_s_setprio(1);
#pragma unroll
    for (int i = 0; i < 4; i++)
#pragma unroll
      for (int j = 0; j < 4; j++)
        acc[i][j + 4] = mfma16(a[i], b1[j], acc[i][j + 4]);
    __builtin_amdgcn_s_setprio(0);
  };

  // prologue: 3 K-steps in flight (12 loads/thread)
  STAGE(0); STAGE(1); STAGE(2);
  // main loop: wait own oldest 4 loads (buf k) -> after barrier everyone's buf[k]
  // is complete; bufs k+1,k+2 stay in flight ACROSS the barrier (counted vmcnt).
  for (int k = 0; k < 38; k++) {
    asm volatile("s_waitcnt vmcnt(8)\n\ts_barrier" ::: "memory");
    if (k < 37) STAGE(k + 3);
    COMP(k);
  }
  asm volatile("s_waitcnt vmcnt(4)\n\ts_barrier" ::: "memory");
  COMP(38);
  asm volatile("s_waitcnt vmcnt(0)\n\ts_barrier" ::: "memory");
  COMP(39);
  __syncthreads();  // all fragment reads done before staging regions become Q/K/Vt

  // ---- epilogue scatter (branchless stride-select): acc + bias ->
  //      sgm 0/1: raw Q (Y) / K (X) @ row*84 + d; sgm 2: Vt transposed @ d*264 + row
#pragma unroll
  for (int j = 0; j < 8; j++) {
    const int col = wn * 128 + j * 16 + lrow;
    if (col < 240) {
      const int sgm = (col >= 160) ? 2 : (col >= 80 ? 1 : 0);
      const int d = col - sgm * 80;
      const float bv = b_qkv[sgm * DIM + h * 80 + d];
      unsigned short* dst = (sgm == 0) ? Y : (sgm == 1) ? X : Vt;
      const int rs = (sgm == 2) ? 1 : TS;
      const int dd = (sgm == 2) ? 264 : 1;
      const int dbase = d * dd;
#pragma unroll
      for (int i = 0; i < 4; i++) {
        const int row = wm * 64 + i * 16 + lq * 4;
#pragma unroll
        for (int r = 0; r < 4; r++)
          dst[(row + r) * rs + dbase] = f2bf(acc[i][j][r] + bv);
      }
    }
  }
  __syncthreads();  // B1: raw Q/K + Vt complete

  // ---- K rope -> regs; Q rope -> A-fragments (wave w owns q-rows w*32..w*32+31) ----
  unsigned short kout[5][8];
  int kro[5], kco[5];
#pragma unroll
  for (int i = 0; i < 5; i++) {
    const int idx = t + i * 512;
    const unsigned r = (unsigned)idx / 10u, c = (unsigned)idx % 10u;
    kro[i] = r; kco[i] = c;
    s16x8 xv = *(const s16x8*)&X[r * TS + c * 8];
    const unsigned cp = (c < 5) ? c + 5 : c - 5;  // partner chunk (+-40 elems)
    s16x8 pv = *(const s16x8*)&X[r * TS + cp * 8];
    const float sgn = (c < 5) ? -1.f : 1.f;
    const float* cf = cosb + (size_t)(s0 + r) * 80 + c * 8;
    const float* sf = sinb + (size_t)(s0 + r) * 80 + c * 8;
#pragma unroll
    for (int j = 0; j < 8; j++)
      kout[i][j] = f2bf(bf2f((unsigned short)xv[j]) * cf[j] +
                        sgn * bf2f((unsigned short)pv[j]) * sf[j]);
  }

  s16x8 aq[2][3];
#pragma unroll
  for (int rt = 0; rt < 2; rt++) {
#pragma unroll
    for (int c = 0; c < 3; c++) {
      const int row = w * 32 + rt * 16 + lrow;
      const int d0 = c * 32 + lq * 8;
      s16x8 fr = {};
      if (d0 < 80) {
        s16x8 xv = *(const s16x8*)&Y[row * TS + d0];
        const int dp = (d0 < 40) ? d0 + 40 : d0 - 40;
        s16x8 pv = *(const s16x8*)&Y[row * TS + dp];
        const float sgn = (d0 < 40) ? -1.f : 1.f;
        const float* cf = cosb + (size_t)(s0 + row) * 80 + d0;
        const float* sf = sinb + (size_t)(s0 + row) * 80 + d0;
#pragma unroll
        for (int j = 0; j < 8; j++)
          fr[j] = (short)f2bf(bf2f((unsigned short)xv[j]) * cf[j] +
                              sgn * bf2f((unsigned short)pv[j]) * sf[j]);
      }
      aq[rt][c] = fr;
    }
  }
  __syncthreads();  // B2: rawK/rawQ reads done

  // ---- write rope'd K at stride 104 (2-way bank aliasing = free) + zero pad ----
#pragma unroll
  for (int i = 0; i < 5; i++)
    *(int4*)&X[kro[i] * 104 + kco[i] * 8] = *(const int4*)kout[i];
  {
    const int r = t >> 1, wh = t & 1;
    const int4 z = {0, 0, 0, 0};
    *(int4*)&X[r * 104 + 80 + wh * 8] = z;
  }
  __syncthreads();  // B3

  // ---- QK^T: 2 row-tiles x 16 col-tiles, K = 96 ----
  fx4 acc2[2][16] = {};
#pragma unroll
  for (int c = 0; c < 3; c++) {
#pragma unroll
    for (int ct = 0; ct < 16; ct++) {
      s16x8 b = *(const s16x8*)&X[(ct * 16 + lrow) * 104 + c * 32 + lq * 8];
      acc2[0][ct] = mfma16(aq[0][c], b, acc2[0][ct]);
      acc2[1][ct] = mfma16(aq[1][c], b, acc2[1][ct]);
    }
  }

  // ---- softmax (rows wave-local: row = rt*16 + lq*4 + r) ----
  const float kscale = 0.11180339887498949f * 1.4426950408889634f;  // 80^-0.5 * log2e
  float inv[2][4];
#pragma unroll
  for (int rt = 0; rt < 2; rt++) {
    float mx[4] = {-1e30f, -1e30f, -1e30f, -1e30f};
#pragma unroll
    for (int ct = 0; ct < 16; ct++)
#pragma unroll
      for (int r = 0; r < 4; r++) mx[r] = fmaxf(mx[r], acc2[rt][ct][r]);
#pragma unroll
    for (int r = 0; r < 4; r++) {
      mx[r] = fmaxf(mx[r], __shfl_xor(mx[r], 1));
      mx[r] = fmaxf(mx[r], __shfl_xor(mx[r], 2));
      mx[r] = fmaxf(mx[r], __shfl_xor(mx[r], 4));
      mx[r] = fmaxf(mx[r], __shfl_xor(mx[r], 8));
    }
    float sm[4] = {0.f, 0.f, 0.f, 0.f};
#pragma unroll
    for (int ct = 0; ct < 16; ct++)
#pragma unroll
      for (int r = 0; r < 4; r++) {
        float e = exp2f((acc2[rt][ct][r] - mx[r]) * kscale);
        acc2[rt][ct][r] = e;
        sm[r] += e;
      }
#pragma unroll
    for (int r = 0; r < 4; r++) {
      sm[r] += __shfl_xor(sm[r], 1);
      sm[r] += __shfl_xor(sm[r], 2);
      sm[r] += __shfl_xor(sm[r], 4);
      sm[r] += __shfl_xor(sm[r], 8);
      inv[rt][r] = 1.f / sm[r];
    }
  }
  __syncthreads();  // B4: Ks dead; X becomes per-wave P-scratch

  // ---- P (rt=0) to per-wave scratch (wave-private; Vt complete since B1) ----
  unsigned short* Pw = X + w * 4224;  // 16 rows x 264 elems
#pragma unroll
  for (int ct = 0; ct < 16; ct++)
#pragma unroll
    for (int r = 0; r < 4; r++)
      Pw[(lq * 4 + r) * 264 + ct * 16 + lrow] = f2bf(acc2[0][ct][r] * inv[0][r]);

  // ---- PV + output, two 16-row sweeps ----
#pragma unroll
  for (int rt = 0; rt < 2; rt++) {
    if (rt == 1) {
#pragma unroll
      for (int ct = 0; ct < 16; ct++)
#pragma unroll
        for (int r = 0; r < 4; r++)
          Pw[(lq * 4 + r) * 264 + ct * 16 + lrow] = f2bf(acc2[1][ct][r] * inv[1][r]);
    }
    fx4 accO[5] = {};
#pragma unroll
    for (int kc = 0; kc < 8; kc++) {
      s16x8 a = *(const s16x8*)&Pw[lrow * 264 + kc * 32 + lq * 8];
#pragma unroll
      for (int tt = 0; tt < 5; tt++) {
        s16x8 b = *(const s16x8*)&Vt[(tt * 16 + lrow) * 264 + kc * 32 + lq * 8];
        accO[tt] = mfma16(a, b, accO[tt]);
      }
    }
    const int srow = s0 + w * 32 + rt * 16 + lq * 4;
#pragma unroll
    for (int tt = 0; tt < 5; tt++) {
      const int col = h * 80 + tt * 16 + lrow;
#pragma unroll
      for (int r = 0; r < 4; r++)
        Ob[(size_t)(srow + r) * DIM + col] = f2bf(accO[tt][r]);
    }
  }
}

// ---------------- proj GEMM: 128x320 tile, BK=64 dbuf, grid 256 = 1 block/CU ----------------
// R6-measured (~20us by the R7 decomposition). Proven vmcnt(0) dbuf schedule;
// 8 waves (2M x 4N), per-wave 64x80 -> 40 MFMA per K-step. XOR-8 swizzle staging.
// LDS 112 KB: As 2x16K @0, Bs 2x40K @32768.
__global__ __launch_bounds__(512, 2) void gemm_proj(const unsigned short* __restrict__ A,
                                                    const unsigned short* __restrict__ Bt,
                                                    const float* __restrict__ bias,
                                                    float* __restrict__ C) {
  __shared__ __attribute__((aligned(16))) char smem[114688];
  char* Abuf = smem;          // 2 x 16384
  char* Bbuf = smem + 32768;  // 2 x 40960

  const int t = threadIdx.x;
  const int lane = t & 63, w = t >> 6;
  const int lrow = lane & 15, lq = lane >> 4;
  const int l7 = lrow & 7;
  const int wm = w >> 2, wn = w & 3;  // 2x4 wave grid, per-wave 64x80 output
  const int m0 = blockIdx.x * 128, n0 = blockIdx.y * 320;

  const int tr3 = t >> 3;  // 0..63
  const int cch = ((t & 7) ^ (tr3 & 7)) * 8;
  const unsigned short* pA = A + (size_t)(m0 + tr3) * 1280 + cch;   // rows tr3, tr3+64
  const unsigned short* pB = Bt + (size_t)(n0 + tr3) * 1280 + cch;  // rows tr3 + i*64

  int offA[4][2], offB[5][2];
#pragma unroll
  for (int i = 0; i < 4; i++) {
    const int ra = wm * 64 + i * 16 + lrow;  // ra & 7 == l7
    offA[i][0] = ra * 128 + (lq ^ l7) * 16;
    offA[i][1] = ra * 128 + ((lq + 4) ^ l7) * 16;
  }
#pragma unroll
  for (int j = 0; j < 5; j++) {
    const int rb = wn * 80 + j * 16 + lrow;  // 80 % 8 == 0 -> rb & 7 == l7
    offB[j][0] = rb * 128 + (lq ^ l7) * 16;
    offB[j][1] = rb * 128 + ((lq + 4) ^ l7) * 16;
  }

  fx4 acc[4][5] = {};

  auto STAGE = [&](int k, int buf) {
    const int kof = k * 64;
    char* da = Abuf + buf * 16384 + w * 1024;
    char* db = Bbuf + buf * 40960 + w * 1024;
    gload_lds16(pA + kof, da);
    gload_lds16(pA + (size_t)64 * 1280 + kof, da + 8192);
#pragma unroll
    for (int i = 0; i < 5; i++)
      gload_lds16(pB + (size_t)i * 64 * 1280 + kof, db + i * 8192);
  };

  STAGE(0, 0);
  for (int k = 0; k < 20; k++) {
    asm volatile("s_waitcnt vmcnt(0)\n\ts_barrier" ::: "memory");
    if (k < 19) STAGE(k + 1, (k + 1) & 1);  // flies during compute(k)
    const char* As = Abuf + (k & 1) * 16384;
    const char* Bs = Bbuf + (k & 1) * 40960;
#pragma unroll
    for (int kq = 0; kq < 2; kq++) {
      s16x8 a[4], b[5];
#pragma unroll
      for (int i = 0; i < 4; i++) a[i] = *(const s16x8*)(As + offA[i][kq]);
#pragma unroll
      for (int j = 0; j < 5; j++) b[j] = *(const s16x8*)(Bs + offB[j][kq]);
      __builtin_amdgcn_s_setprio(1);
#pragma unroll
      for (int i = 0; i < 4; i++)
#pragma unroll
        for (int j = 0; j < 5; j++)
          acc[i][j] = mfma16(a[i], b[j], acc[i][j]);
      __builtin_amdgcn_s_setprio(0);
    }
  }

  // epilogue: acc + bias -> C (f32)
#pragma unroll
  for (int i = 0; i < 4; i++) {
    const int row_base = m0 + wm * 64 + i * 16 + lq * 4;
#pragma unroll
    for (int j = 0; j < 5; j++) {
      const int col = n0 + wn * 80 + j * 16 + lrow;
      const float bv = bias[col];
#pragma unroll
      for (int r = 0; r < 4; r++)
        C[(size_t)(row_base + r) * DIM + col] = acc[i][j][r] + bv;
    }
  }
}

// ---------------- launch ----------------
extern "C" void kernel_launch(void* const* d_in, const int* in_sizes, int n_in,
                              void* d_out, int out_size, void* d_ws, size_t ws_size,
                              hipStream_t stream) {
  const float* hidden = (const float*)d_in[0];
  // d_in[1] = cu_seqlens: fixed layout (32 chunks of 256), unused
  const float* cosb = (const float*)d_in[2];
  const float* sinb = (const float*)d_in[3];
  const float* w_qkv = (const float*)d_in[4];
  const float* b_qkv = (const float*)d_in[5];
  const float* w_proj = (const float*)d_in[6];
  const float* b_proj = (const float*)d_in[7];
  float* out = (float*)d_out;

  // workspace layout (bytes)
  char* ws = (char*)d_ws;
  constexpr size_t HB_B = (size_t)SEQ * DIM * 2;    // 20,971,520 hidden bf16
  constexpr size_t WQT_B = (size_t)NQKV * DIM * 2;  //  9,830,400 w_qkv^T bf16
  constexpr size_t WPT_B = (size_t)DIM * DIM * 2;   //  3,276,800 w_proj^T bf16
  constexpr size_t OB_B = (size_t)SEQ * DIM * 2;    // 20,971,520 attn out bf16
  size_t off = 0;
  unsigned short* hb = (unsigned short*)(ws + off);     off += HB_B;
  unsigned short* wqkvT = (unsigned short*)(ws + off);  off += WQT_B;
  unsigned short* wprojT = (unsigned short*)(ws + off); off += WPT_B;
  unsigned short* Ob = (unsigned short*)(ws + off);     off += OB_B;
  if (ws_size < off) return;

  // 1. fused prep: cast hidden + transpose-cast w_qkv/w_proj (one launch)
  prep_kernel<<<dim3(16640), dim3(256), 0, stream>>>(hidden, hb, w_qkv, wqkvT,
                                                     w_proj, wprojT);
  // 2. mega: QKV GEMM + RoPE + attention -> Ob (8-wave, two-phase clustered COMP)
  mega_attn<<<dim3(NIMG, HEADS), dim3(512), 0, stream>>>(hb, wqkvT, b_qkv, cosb, sinb, Ob);
  // 3. proj GEMM (+bias) -> d_out (f32), 128x320 tiles, grid 256
  gemm_proj<<<dim3(SEQ / 128, DIM / 320), dim3(512), 0, stream>>>(
      Ob, wprojT, b_proj, out);
}

// Round 10
// 258.185 us; speedup vs baseline: 1.6011x; 1.0487x over previous
//
#include <hip/hip_runtime.h>
#include <stdint.h>

#define DEVFN __device__ __forceinline__

typedef short s16x8 __attribute__((ext_vector_type(8)));
typedef __bf16 bf16x8 __attribute__((ext_vector_type(8)));
typedef float fx4 __attribute__((ext_vector_type(4)));

// Problem constants (fixed by the reference)
constexpr int SEQ = 8192, DIM = 1280, HEADS = 16;
constexpr int NIMG = 32;
constexpr int NQKV = 3840;  // 3*DIM
constexpr int TS = 84;      // raw Q/K tile stride (168B rows: scatter = 2 lanes/bank, free)

DEVFN unsigned short f2bf(float f) {
  union { float f; unsigned u; } v; v.f = f;
  unsigned r = v.u + 0x7FFFu + ((v.u >> 16) & 1u);  // RNE
  return (unsigned short)(r >> 16);
}
DEVFN float bf2f(unsigned short u) {
  union { unsigned u; float f; } v; v.u = ((unsigned)u) << 16;
  return v.f;
}

DEVFN fx4 mfma16(s16x8 a, s16x8 b, fx4 c) {
  return __builtin_amdgcn_mfma_f32_16x16x32_bf16(
      __builtin_bit_cast(bf16x8, a), __builtin_bit_cast(bf16x8, b), c, 0, 0, 0);
}

DEVFN void gload_lds16(const void* g, void* l) {
  // global -> LDS direct, 16B per lane; LDS dest = wave-uniform base + lane*16
  __builtin_amdgcn_global_load_lds(
      (__attribute__((address_space(1))) void*)(uintptr_t)g,
      (__attribute__((address_space(3))) void*)l, 16, 0, 0);
}

// ---------------- fused prep: cast hidden + transpose-cast both weights ----------------
__global__ __launch_bounds__(256) void prep_kernel(const float* __restrict__ hidden,
                                                   unsigned short* __restrict__ hb,
                                                   const float* __restrict__ w_qkv,
                                                   unsigned short* __restrict__ wqkvT,
                                                   const float* __restrict__ w_proj,
                                                   unsigned short* __restrict__ wprojT) {
  const int b = blockIdx.x;
  if (b < 10240) {  // cast: 10240*256*4 = SEQ*DIM exactly
    const int i = b * 256 + threadIdx.x;
    float4 v = ((const float4*)hidden)[i];
    ushort4 o;
    o.x = f2bf(v.x); o.y = f2bf(v.y); o.z = f2bf(v.z); o.w = f2bf(v.w);
    ((ushort4*)hb)[i] = o;
    return;
  }
  __shared__ float tile[32][33];
  const float* W; unsigned short* T;
  int K, N, bx, by;
  if (b < 15040) {
    const int bb = b - 10240;
    bx = bb % 120; by = bb / 120; W = w_qkv; T = wqkvT; K = DIM; N = NQKV;
  } else {
    const int bb = b - 15040;
    bx = bb % 40; by = bb / 40; W = w_proj; T = wprojT; K = DIM; N = DIM;
  }
  const int tx = threadIdx.x & 31, ty = threadIdx.x >> 5;  // 32x8
  const int n0 = bx * 32, k0 = by * 32;
#pragma unroll
  for (int i = 0; i < 4; i++) {
    int r = ty + i * 8;
    tile[r][tx] = W[(size_t)(k0 + r) * N + n0 + tx];
  }
  __syncthreads();
#pragma unroll
  for (int i = 0; i < 4; i++) {
    int r = ty + i * 8;
    T[(size_t)(n0 + r) * K + k0 + tx] = f2bf(tile[tx][r]);
  }
}

// ---------------- mega kernel: QKV GEMM + bias + RoPE + attention ----------------
// R10: m201-style 4-phase K-loop. BK=64, double-buffered, PER-HALF-TILE staging
// (4 half-tiles/K-tile, 2 gload_lds/thread each). Each phase: {stage 1 half-tile +
// burst ds_reads (issued BEFORE the barrier so latency hides under barrier wait) ->
// s_barrier -> lgkmcnt(0)+sched_barrier -> setprio'd 16-MFMA quadrant}. Counted
// vmcnt(2) once per K-tile (A0(kt+1)'s 2 loads stay in flight across it; final tile
// uses vmcnt(0) since its successor stages are skipped). Stage->phase mapping:
// kt.p0=A1(kt+1), p1=B0(kt+1), p2=B1(kt+1) (all target the OTHER buffer),
// p3=A0(kt+2) (targets current buf A-half0, last read at p2: guarded by p2's
// barrier + >=200cy DMA latency vs <=120cy lgkm drain).
// Wave grid 2Mx4N (wm=w>>2, wn=w&3): per-wave 128x64 output, acc[8][4].
// Attention section (epilogue scatter / rope / QK^T / softmax / PV): FROZEN from
// R3-R9 except scatter re-indexed for the new acc mapping.
// LDS (153600 B): Abuf 2x32K @0 (buf d: half h at d*32768+h*16384), Bbuf @65536
// same (dead after K-loop); X@0 (rawK84 -> Ks[256][104] -> P-scratch 8x16x264),
// Y@67584 (rawQ84), Vt@110592 (80x264).
__global__ __launch_bounds__(512, 2) void mega_attn(const unsigned short* __restrict__ hb,
                                                    const unsigned short* __restrict__ wqkvT,
                                                    const float* __restrict__ b_qkv,
                                                    const float* __restrict__ cosb,
                                                    const float* __restrict__ sinb,
                                                    unsigned short* __restrict__ Ob) {
  __shared__ __attribute__((aligned(16))) char smem[153600];
  unsigned short* X = (unsigned short*)smem;
  unsigned short* Y = (unsigned short*)(smem + 67584);
  unsigned short* Vt = (unsigned short*)(smem + 110592);  // [80][264]
  char* Abuf = smem;          // 2 x 32768 (half h at +h*16384)
  char* Bbuf = smem + 65536;  // 2 x 32768

  const int t = threadIdx.x;
  const int lane = t & 63, w = t >> 6;
  const int lrow = lane & 15, lq = lane >> 4;
  const int l7 = lrow & 7;
  const int n = blockIdx.x, h = blockIdx.y;
  const int s0 = n * 256;
  const int wm = w >> 2, wn = w & 3;  // 2x4 wave grid, per-wave 128x64 output

  // staging geometry (per half-tile = 128 rows x 64 cols = 1024 16B-chunks):
  // thread covers chunks t (row t>>3) and t+512 (row 64+(t>>3)); stored pos t&7
  // holds global chunk (t&7)^(row&7) (XOR-8 -> conflict-free ds_read_b128).
  const int tr3 = t >> 3;  // 0..63
  const int cch = ((t & 7) ^ (tr3 & 7)) * 8;
  const unsigned short* pA4[4];
  const unsigned short* pB4[4];
#pragma unroll
  for (int q = 0; q < 4; q++) {
    pA4[q] = hb + (size_t)(s0 + q * 64 + tr3) * 1280 + cch;
    const int col = q * 64 + tr3;
    const int cc = col < 240 ? col : 239;  // pad cols clamp (240..255 never used)
    const int sgm = (cc >= 160) ? 2 : (cc >= 80 ? 1 : 0);
    pB4[q] = wqkvT + (size_t)(sgm * DIM + h * 80 + (cc - sgm * 80)) * 1280 + cch;
  }

  // fragment read offsets (within a 16KB half): row*128B + swizzled chunk.
  // A-half = wm (rows wm*128+i*16+lrow, in-half row i*16+lrow); B-half = wn>>1
  // (in-half row (wn&1)*64+j*16+lrow). row&7 == l7 in both cases.
  int offA[8][2], offB[4][2];
#pragma unroll
  for (int i = 0; i < 8; i++) {
#pragma unroll
    for (int kq = 0; kq < 2; kq++)
      offA[i][kq] = (i * 16 + lrow) * 128 + ((kq * 4 + lq) ^ l7) * 16;
  }
#pragma unroll
  for (int j = 0; j < 4; j++) {
#pragma unroll
    for (int kq = 0; kq < 2; kq++)
      offB[j][kq] = ((wn & 1) * 64 + j * 16 + lrow) * 128 + ((kq * 4 + lq) ^ l7) * 16;
  }

  fx4 acc[8][4] = {};

  auto STG = [&](char* mbase, const unsigned short* const* p4, int kt2, int hf) {
    char* d = mbase + (kt2 & 1) * 32768 + hf * 16384 + w * 1024;
    gload_lds16(p4[hf * 2 + 0] + kt2 * 64, d);
    gload_lds16(p4[hf * 2 + 1] + kt2 * 64, d + 8192);
  };

  // prologue: all 4 halves of kt=0 + A0(kt=1) = 10 loads/thread in flight
  STG(Abuf, pA4, 0, 0); STG(Abuf, pA4, 0, 1);
  STG(Bbuf, pB4, 0, 0); STG(Bbuf, pB4, 0, 1);
  STG(Abuf, pA4, 1, 0);

  for (int kt = 0; kt < 20; kt++) {
    const char* As = Abuf + (kt & 1) * 32768 + wm * 16384;
    const char* Bs = Bbuf + (kt & 1) * 32768 + (wn >> 1) * 16384;
    s16x8 a[8], b0, b1, b2, b3;

    // ---- phase 0: buf[kt] handshake; stage A1(kt+1); a[kq0]+b01[kq0]; 16 MFMA
    if (kt == 19) asm volatile("s_waitcnt vmcnt(0)" ::: "memory");
    else          asm volatile("s_waitcnt vmcnt(2)" ::: "memory");
    __builtin_amdgcn_s_barrier();
    if (kt < 19) STG(Abuf, pA4, kt + 1, 1);
#pragma unroll
    for (int i = 0; i < 8; i++) a[i] = *(const s16x8*)(As + offA[i][0]);
    b0 = *(const s16x8*)(Bs + offB[0][0]);
    b1 = *(const s16x8*)(Bs + offB[1][0]);
    __builtin_amdgcn_s_barrier();
    asm volatile("s_waitcnt lgkmcnt(0)" ::: "memory");
    __builtin_amdgcn_sched_barrier(0);
    __builtin_amdgcn_s_setprio(1);
#pragma unroll
    for (int i = 0; i < 8; i++) {
      acc[i][0] = mfma16(a[i], b0, acc[i][0]);
      acc[i][1] = mfma16(a[i], b1, acc[i][1]);
    }
    __builtin_amdgcn_s_setprio(0);

    // ---- phase 1: stage B0(kt+1); b23[kq0]; 16 MFMA
    if (kt < 19) STG(Bbuf, pB4, kt + 1, 0);
    b2 = *(const s16x8*)(Bs + offB[2][0]);
    b3 = *(const s16x8*)(Bs + offB[3][0]);
    __builtin_amdgcn_s_barrier();
    asm volatile("s_waitcnt lgkmcnt(0)" ::: "memory");
    __builtin_amdgcn_sched_barrier(0);
    __builtin_amdgcn_s_setprio(1);
#pragma unroll
    for (int i = 0; i < 8; i++) {
      acc[i][2] = mfma16(a[i], b2, acc[i][2]);
      acc[i][3] = mfma16(a[i], b3, acc[i][3]);
    }
    __builtin_amdgcn_s_setprio(0);

    // ---- phase 2: stage B1(kt+1); a[kq1]+b01[kq1]; 16 MFMA
    if (kt < 19) STG(Bbuf, pB4, kt + 1, 1);
#pragma unroll
    for (int i = 0; i < 8; i++) a[i] = *(const s16x8*)(As + offA[i][1]);
    b0 = *(const s16x8*)(Bs + offB[0][1]);
    b1 = *(const s16x8*)(Bs + offB[1][1]);
    __builtin_amdgcn_s_barrier();
    asm volatile("s_waitcnt lgkmcnt(0)" ::: "memory");
    __builtin_amdgcn_sched_barrier(0);
    __builtin_amdgcn_s_setprio(1);
#pragma unroll
    for (int i = 0; i < 8; i++) {
      acc[i][0] = mfma16(a[i], b0, acc[i][0]);
      acc[i][1] = mfma16(a[i], b1, acc[i][1]);
    }
    __builtin_amdgcn_s_setprio(0);

    // ---- phase 3: stage A0(kt+2) (current buf, A-half0 reads done at p2); b23[kq1]
    if (kt < 18) STG(Abuf, pA4, kt + 2, 0);
    b2 = *(const s16x8*)(Bs + offB[2][1]);
    b3 = *(const s16x8*)(Bs + offB[3][1]);
    __builtin_amdgcn_s_barrier();
    asm volatile("s_waitcnt lgkmcnt(0)" ::: "memory");
    __builtin_amdgcn_sched_barrier(0);
    __builtin_amdgcn_s_setprio(1);
#pragma unroll
    for (int i = 0; i < 8; i++) {
      acc[i][2] = mfma16(a[i], b2, acc[i][2]);
      acc[i][3] = mfma16(a[i], b3, acc[i][3]);
    }
    __builtin_amdgcn_s_setprio(0);
  }
  __syncthreads();  // all fragment reads done before staging regions become Q/K/Vt

  // ---- epilogue scatter (branchless stride-select, re-indexed for acc[8][4]):
  //      sgm 0/1: raw Q (Y) / K (X) @ row*84 + d; sgm 2: Vt transposed @ d*264 + row
#pragma unroll
  for (int j = 0; j < 4; j++) {
    const int col = wn * 64 + j * 16 + lrow;
    if (col < 240) {
      const int sgm = (col >= 160) ? 2 : (col >= 80 ? 1 : 0);
      const int d = col - sgm * 80;
      const float bv = b_qkv[sgm * DIM + h * 80 + d];
      unsigned short* dst = (sgm == 0) ? Y : (sgm == 1) ? X : Vt;
      const int rs = (sgm == 2) ? 1 : TS;
      const int dd = (sgm == 2) ? 264 : 1;
      const int dbase = d * dd;
#pragma unroll
      for (int i = 0; i < 8; i++) {
        const int row = wm * 128 + i * 16 + lq * 4;
#pragma unroll
        for (int r = 0; r < 4; r++)
          dst[(row + r) * rs + dbase] = f2bf(acc[i][j][r] + bv);
      }
    }
  }
  __syncthreads();  // B1: raw Q/K + Vt complete

  // ---- K rope -> regs; Q rope -> A-fragments (wave w owns q-rows w*32..w*32+31) ----
  unsigned short kout[5][8];
  int kro[5], kco[5];
#pragma unroll
  for (int i = 0; i < 5; i++) {
    const int idx = t + i * 512;
    const unsigned r = (unsigned)idx / 10u, c = (unsigned)idx % 10u;
    kro[i] = r; kco[i] = c;
    s16x8 xv = *(const s16x8*)&X[r * TS + c * 8];
    const unsigned cp = (c < 5) ? c + 5 : c - 5;  // partner chunk (+-40 elems)
    s16x8 pv = *(const s16x8*)&X[r * TS + cp * 8];
    const float sgn = (c < 5) ? -1.f : 1.f;
    const float* cf = cosb + (size_t)(s0 + r) * 80 + c * 8;
    const float* sf = sinb + (size_t)(s0 + r) * 80 + c * 8;
#pragma unroll
    for (int j = 0; j < 8; j++)
      kout[i][j] = f2bf(bf2f((unsigned short)xv[j]) * cf[j] +
                        sgn * bf2f((unsigned short)pv[j]) * sf[j]);
  }

  s16x8 aq[2][3];
#pragma unroll
  for (int rt = 0; rt < 2; rt++) {
#pragma unroll
    for (int c = 0; c < 3; c++) {
      const int row = w * 32 + rt * 16 + lrow;
      const int d0 = c * 32 + lq * 8;
      s16x8 fr = {};
      if (d0 < 80) {
        s16x8 xv = *(const s16x8*)&Y[row * TS + d0];
        const int dp = (d0 < 40) ? d0 + 40 : d0 - 40;
        s16x8 pv = *(const s16x8*)&Y[row * TS + dp];
        const float sgn = (d0 < 40) ? -1.f : 1.f;
        const float* cf = cosb + (size_t)(s0 + row) * 80 + d0;
        const float* sf = sinb + (size_t)(s0 + row) * 80 + d0;
#pragma unroll
        for (int j = 0; j < 8; j++)
          fr[j] = (short)f2bf(bf2f((unsigned short)xv[j]) * cf[j] +
                              sgn * bf2f((unsigned short)pv[j]) * sf[j]);
      }
      aq[rt][c] = fr;
    }
  }
  __syncthreads();  // B2: rawK/rawQ reads done

  // ---- write rope'd K at stride 104 (2-way bank aliasing = free) + zero pad ----
#pragma unroll
  for (int i = 0; i < 5; i++)
    *(int4*)&X[kro[i] * 104 + kco[i] * 8] = *(const int4*)kout[i];
  {
    const int r = t >> 1, wh = t & 1;
    const int4 z = {0, 0, 0, 0};
    *(int4*)&X[r * 104 + 80 + wh * 8] = z;
  }
  __syncthreads();  // B3

  // ---- QK^T: 2 row-tiles x 16 col-tiles, K = 96 ----
  fx4 acc2[2][16] = {};
#pragma unroll
  for (int c = 0; c < 3; c++) {
#pragma unroll
    for (int ct = 0; ct < 16; ct++) {
      s16x8 b = *(const s16x8*)&X[(ct * 16 + lrow) * 104 + c * 32 + lq * 8];
      acc2[0][ct] = mfma16(aq[0][c], b, acc2[0][ct]);
      acc2[1][ct] = mfma16(aq[1][c], b, acc2[1][ct]);
    }
  }

  // ---- softmax (rows wave-local: row = rt*16 + lq*4 + r) ----
  const float kscale = 0.11180339887498949f * 1.4426950408889634f;  // 80^-0.5 * log2e
  float inv[2][4];
#pragma unroll
  for (int rt = 0; rt < 2; rt++) {
    float mx[4] = {-1e30f, -1e30f, -1e30f, -1e30f};
#pragma unroll
    for (int ct = 0; ct < 16; ct++)
#pragma unroll
      for (int r = 0; r < 4; r++) mx[r] = fmaxf(mx[r], acc2[rt][ct][r]);
#pragma unroll
    for (int r = 0; r < 4; r++) {
      mx[r] = fmaxf(mx[r], __shfl_xor(mx[r], 1));
      mx[r] = fmaxf(mx[r], __shfl_xor(mx[r], 2));
      mx[r] = fmaxf(mx[r], __shfl_xor(mx[r], 4));
      mx[r] = fmaxf(mx[r], __shfl_xor(mx[r], 8));
    }
    float sm[4] = {0.f, 0.f, 0.f, 0.f};
#pragma unroll
    for (int ct = 0; ct < 16; ct++)
#pragma unroll
      for (int r = 0; r < 4; r++) {
        float e = exp2f((acc2[rt][ct][r] - mx[r]) * kscale);
        acc2[rt][ct][r] = e;
        sm[r] += e;
      }
#pragma unroll
    for (int r = 0; r < 4; r++) {
      sm[r] += __shfl_xor(sm[r], 1);
      sm[r] += __shfl_xor(sm[r], 2);
      sm[r] += __shfl_xor(sm[r], 4);
      sm[r] += __shfl_xor(sm[r], 8);
      inv[rt][r] = 1.f / sm[r];
    }
  }
  __syncthreads();  // B4: Ks dead; X becomes per-wave P-scratch

  // ---- P (rt=0) to per-wave scratch (wave-private; Vt complete since B1) ----
  unsigned short* Pw = X + w * 4224;  // 16 rows x 264 elems
#pragma unroll
  for (int ct = 0; ct < 16; ct++)
#pragma unroll
    for (int r = 0; r < 4; r++)
      Pw[(lq * 4 + r) * 264 + ct * 16 + lrow] = f2bf(acc2[0][ct][r] * inv[0][r]);

  // ---- PV + output, two 16-row sweeps ----
#pragma unroll
  for (int rt = 0; rt < 2; rt++) {
    if (rt == 1) {
#pragma unroll
      for (int ct = 0; ct < 16; ct++)
#pragma unroll
        for (int r = 0; r < 4; r++)
          Pw[(lq * 4 + r) * 264 + ct * 16 + lrow] = f2bf(acc2[1][ct][r] * inv[1][r]);
    }
    fx4 accO[5] = {};
#pragma unroll
    for (int kc = 0; kc < 8; kc++) {
      s16x8 a = *(const s16x8*)&Pw[lrow * 264 + kc * 32 + lq * 8];
#pragma unroll
      for (int tt = 0; tt < 5; tt++) {
        s16x8 b = *(const s16x8*)&Vt[(tt * 16 + lrow) * 264 + kc * 32 + lq * 8];
        accO[tt] = mfma16(a, b, accO[tt]);
      }
    }
    const int srow = s0 + w * 32 + rt * 16 + lq * 4;
#pragma unroll
    for (int tt = 0; tt < 5; tt++) {
      const int col = h * 80 + tt * 16 + lrow;
#pragma unroll
      for (int r = 0; r < 4; r++)
        Ob[(size_t)(srow + r) * DIM + col] = f2bf(accO[tt][r]);
    }
  }
}

// ---------------- proj GEMM: 128x320 tile, BK=64 dbuf, grid 256 = 1 block/CU ----------------
// R6-measured (~20us by the R7 decomposition). Proven vmcnt(0) dbuf schedule;
// 8 waves (2M x 4N), per-wave 64x80 -> 40 MFMA per K-step. XOR-8 swizzle staging.
// LDS 112 KB: As 2x16K @0, Bs 2x40K @32768.
__global__ __launch_bounds__(512, 2) void gemm_proj(const unsigned short* __restrict__ A,
                                                    const unsigned short* __restrict__ Bt,
                                                    const float* __restrict__ bias,
                                                    float* __restrict__ C) {
  __shared__ __attribute__((aligned(16))) char smem[114688];
  char* Abuf = smem;          // 2 x 16384
  char* Bbuf = smem + 32768;  // 2 x 40960

  const int t = threadIdx.x;
  const int lane = t & 63, w = t >> 6;
  const int lrow = lane & 15, lq = lane >> 4;
  const int l7 = lrow & 7;
  const int wm = w >> 2, wn = w & 3;  // 2x4 wave grid, per-wave 64x80 output
  const int m0 = blockIdx.x * 128, n0 = blockIdx.y * 320;

  const int tr3 = t >> 3;  // 0..63
  const int cch = ((t & 7) ^ (tr3 & 7)) * 8;
  const unsigned short* pA = A + (size_t)(m0 + tr3) * 1280 + cch;   // rows tr3, tr3+64
  const unsigned short* pB = Bt + (size_t)(n0 + tr3) * 1280 + cch;  // rows tr3 + i*64

  int offA[4][2], offB[5][2];
#pragma unroll
  for (int i = 0; i < 4; i++) {
    const int ra = wm * 64 + i * 16 + lrow;  // ra & 7 == l7
    offA[i][0] = ra * 128 + (lq ^ l7) * 16;
    offA[i][1] = ra * 128 + ((lq + 4) ^ l7) * 16;
  }
#pragma unroll
  for (int j = 0; j < 5; j++) {
    const int rb = wn * 80 + j * 16 + lrow;  // 80 % 8 == 0 -> rb & 7 == l7
    offB[j][0] = rb * 128 + (lq ^ l7) * 16;
    offB[j][1] = rb * 128 + ((lq + 4) ^ l7) * 16;
  }

  fx4 acc[4][5] = {};

  auto STAGE = [&](int k, int buf) {
    const int kof = k * 64;
    char* da = Abuf + buf * 16384 + w * 1024;
    char* db = Bbuf + buf * 40960 + w * 1024;
    gload_lds16(pA + kof, da);
    gload_lds16(pA + (size_t)64 * 1280 + kof, da + 8192);
#pragma unroll
    for (int i = 0; i < 5; i++)
      gload_lds16(pB + (size_t)i * 64 * 1280 + kof, db + i * 8192);
  };

  STAGE(0, 0);
  for (int k = 0; k < 20; k++) {
    asm volatile("s_waitcnt vmcnt(0)\n\ts_barrier" ::: "memory");
    if (k < 19) STAGE(k + 1, (k + 1) & 1);  // flies during compute(k)
    const char* As = Abuf + (k & 1) * 16384;
    const char* Bs = Bbuf + (k & 1) * 40960;
#pragma unroll
    for (int kq = 0; kq < 2; kq++) {
      s16x8 a[4], b[5];
#pragma unroll
      for (int i = 0; i < 4; i++) a[i] = *(const s16x8*)(As + offA[i][kq]);
#pragma unroll
      for (int j = 0; j < 5; j++) b[j] = *(const s16x8*)(Bs + offB[j][kq]);
      __builtin_amdgcn_s_setprio(1);
#pragma unroll
      for (int i = 0; i < 4; i++)
#pragma unroll
        for (int j = 0; j < 5; j++)
          acc[i][j] = mfma16(a[i], b[j], acc[i][j]);
      __builtin_amdgcn_s_setprio(0);
    }
  }

  // epilogue: acc + bias -> C (f32)
#pragma unroll
  for (int i = 0; i < 4; i++) {
    const int row_base = m0 + wm * 64 + i * 16 + lq * 4;
#pragma unroll
    for (int j = 0; j < 5; j++) {
      const int col = n0 + wn * 80 + j * 16 + lrow;
      const float bv = bias[col];
#pragma unroll
      for (int r = 0; r < 4; r++)
        C[(size_t)(row_base + r) * DIM + col] = acc[i][j][r] + bv;
    }
  }
}

// ---------------- launch ----------------
extern "C" void kernel_launch(void* const* d_in, const int* in_sizes, int n_in,
                              void* d_out, int out_size, void* d_ws, size_t ws_size,
                              hipStream_t stream) {
  const float* hidden = (const float*)d_in[0];
  // d_in[1] = cu_seqlens: fixed layout (32 chunks of 256), unused
  const float* cosb = (const float*)d_in[2];
  const float* sinb = (const float*)d_in[3];
  const float* w_qkv = (const float*)d_in[4];
  const float* b_qkv = (const float*)d_in[5];
  const float* w_proj = (const float*)d_in[6];
  const float* b_proj = (const float*)d_in[7];
  float* out = (float*)d_out;

  // workspace layout (bytes)
  char* ws = (char*)d_ws;
  constexpr size_t HB_B = (size_t)SEQ * DIM * 2;    // 20,971,520 hidden bf16
  constexpr size_t WQT_B = (size_t)NQKV * DIM * 2;  //  9,830,400 w_qkv^T bf16
  constexpr size_t WPT_B = (size_t)DIM * DIM * 2;   //  3,276,800 w_proj^T bf16
  constexpr size_t OB_B = (size_t)SEQ * DIM * 2;    // 20,971,520 attn out bf16
  size_t off = 0;
  unsigned short* hb = (unsigned short*)(ws + off);     off += HB_B;
  unsigned short* wqkvT = (unsigned short*)(ws + off);  off += WQT_B;
  unsigned short* wprojT = (unsigned short*)(ws + off); off += WPT_B;
  unsigned short* Ob = (unsigned short*)(ws + off);     off += OB_B;
  if (ws_size < off) return;

  // 1. fused prep: cast hidden + transpose-cast w_qkv/w_proj (one launch)
  prep_kernel<<<dim3(16640), dim3(256), 0, stream>>>(hidden, hb, w_qkv, wqkvT,
                                                     w_proj, wprojT);
  // 2. mega: QKV GEMM + RoPE + attention -> Ob (m201-style 4-phase K-loop)
  mega_attn<<<dim3(NIMG, HEADS), dim3(512), 0, stream>>>(hb, wqkvT, b_qkv, cosb, sinb, Ob);
  // 3. proj GEMM (+bias) -> d_out (f32), 128x320 tiles, grid 256
  gemm_proj<<<dim3(SEQ / 128, DIM / 320), dim3(512), 0, stream>>>(
      Ob, wprojT, b_proj, out);
}